// Round 1
// baseline (732.861 us; speedup 1.0000x reference)
//
#include <hip/hip_runtime.h>

// Problem constants (match reference): B=16384, L=50, V=1e6, D=128
#define B_SZ 16384
#define L_SZ 50
#define D_SZ 128

// Tiny pre-kernel: WT[k][j] = W[j][k]  (128x128 fp32, 64 KB -> d_ws)
__global__ void transpose_w_kernel(const float* __restrict__ W,
                                   float* __restrict__ WT) {
    int t = blockIdx.x * 256 + threadIdx.x;     // 0..16383
    int j = t >> 7;
    int k = t & 127;
    WT[k * D_SZ + j] = W[j * D_SZ + k];
}

// Fused gather-sum + (s @ W.T + b).
// One wave per batch row; lane i owns output elements {2i, 2i+1}.
// s (the summed embedding) lives distributed across the wave (2 floats/lane);
// the matmul broadcasts s[k] via v_readlane (compile-time lane index after
// full unroll) and streams WT coalesced (L2-resident, 64 KB).
__global__ __launch_bounds__(256) void fused_event_emb_kernel(
    const int* __restrict__ entities,
    const int* __restrict__ history,
    const int* __restrict__ hist_len,
    const float* __restrict__ emb,
    const float* __restrict__ WT,
    const float* __restrict__ bias,
    float* __restrict__ out,
    int total_waves) {
    const int lane = threadIdx.x & 63;
    const int wave = __builtin_amdgcn_readfirstlane((int)(threadIdx.x >> 6));
    const int gwave = blockIdx.x * 4 + wave;

    const float2* emb2 = (const float2*)emb;
    const float2* wt2  = (const float2*)WT;    // [128][64] float2
    const float2* b2   = (const float2*)bias;  // [64] float2
    float2* out2       = (float2*)out;

    for (int r = gwave; r < B_SZ; r += total_waves) {
        const int hl = __builtin_amdgcn_readfirstlane(hist_len[r]);

        float2 acc = make_float2(0.0f, 0.0f);
        if (hl == 0) {
            // Empty history -> entity's own embedding.
            const int e = entities[r];
            acc = emb2[(size_t)e * 64 + lane];
        } else {
            const int* hrow = history + r * L_SZ;
            int l = 0;
            // Unroll x4 for memory-level parallelism (hide ~900cy HBM latency).
            for (; l + 4 <= hl; l += 4) {
                const int i0 = hrow[l + 0];
                const int i1 = hrow[l + 1];
                const int i2 = hrow[l + 2];
                const int i3 = hrow[l + 3];
                float2 v0 = emb2[(size_t)i0 * 64 + lane];
                float2 v1 = emb2[(size_t)i1 * 64 + lane];
                float2 v2 = emb2[(size_t)i2 * 64 + lane];
                float2 v3 = emb2[(size_t)i3 * 64 + lane];
                acc.x += (v0.x + v1.x) + (v2.x + v3.x);
                acc.y += (v0.y + v1.y) + (v2.y + v3.y);
            }
            for (; l < hl; ++l) {
                const int i0 = hrow[l];
                float2 v0 = emb2[(size_t)i0 * 64 + lane];
                acc.x += v0.x;
                acc.y += v0.y;
            }
        }

        // out[r][j] = bias[j] + sum_k s[k] * WT[k][j],  lane owns j=2*lane,2*lane+1
        float2 o = b2[lane];
        const unsigned sx = __float_as_uint(acc.x);
        const unsigned sy = __float_as_uint(acc.y);
#pragma unroll
        for (int k = 0; k < D_SZ; ++k) {
            // After unroll, (k>>1) is a literal -> v_readlane_b32 to SGPR.
            const unsigned su =
                __builtin_amdgcn_readlane((k & 1) ? sy : sx, k >> 1);
            const float sk = __uint_as_float(su);
            const float2 w = wt2[k * 64 + lane];
            o.x = fmaf(sk, w.x, o.x);
            o.y = fmaf(sk, w.y, o.y);
        }
        out2[(size_t)r * 64 + lane] = o;
    }
}

extern "C" void kernel_launch(void* const* d_in, const int* in_sizes, int n_in,
                              void* d_out, int out_size, void* d_ws,
                              size_t ws_size, hipStream_t stream) {
    const int* entities   = (const int*)d_in[0];
    const int* history    = (const int*)d_in[1];
    const int* hist_len   = (const int*)d_in[2];
    const float* emb      = (const float*)d_in[3];
    const float* W        = (const float*)d_in[4];
    const float* bias     = (const float*)d_in[5];

    float* WT = (float*)d_ws;  // 64 KB scratch for transposed W

    transpose_w_kernel<<<64, 256, 0, stream>>>(W, WT);

    const int blocks = 2048;               // 4 waves/block -> 8192 waves, 2 rows/wave
    const int total_waves = blocks * 4;
    fused_event_emb_kernel<<<blocks, 256, 0, stream>>>(
        entities, history, hist_len, emb, WT, bias, (float*)d_out, total_waves);
}

// Round 2
// 611.371 us; speedup vs baseline: 1.1987x; 1.1987x over previous
//
#include <hip/hip_runtime.h>

// Problem constants (match reference): B=16384, L=50, V=1e6, D=128
#define B_SZ 16384
#define L_SZ 50
#define D_SZ 128
#define BLOCK_THREADS 1024
#define WAVES_PER_BLOCK 16
#define GRID_BLOCKS 512
#define TOTAL_WAVES (GRID_BLOCKS * WAVES_PER_BLOCK)  // 8192 -> 2 rows/wave

// Fused: gather-sum + (s @ W.T + b), W held transposed+swizzled in LDS.
// 16 waves/block, 64 KB LDS -> 2 blocks/CU -> 32 waves/CU (full occupancy).
// XOR swizzle: WT[k][j ^ ((2k)&62)]. Staging writes are ~4-way conflicted
// (one-time); matmul reads per k cover one contiguous 512B line (conflict-free).
__global__ __launch_bounds__(BLOCK_THREADS, 8) void fused_event_emb_kernel(
    const int* __restrict__ entities,
    const int* __restrict__ history,
    const int* __restrict__ hist_len,
    const float* __restrict__ emb,
    const float* __restrict__ W,
    const float* __restrict__ bias,
    float* __restrict__ out) {
    __shared__ float wt_lds[D_SZ * D_SZ];  // exactly 64 KB

    const int tid = threadIdx.x;

    // Stage W[j][k] -> wt_lds[k][j ^ ((2k)&62)], coalesced global reads.
#pragma unroll
    for (int i = 0; i < (D_SZ * D_SZ) / BLOCK_THREADS; ++i) {  // 16 iters
        const int idx = i * BLOCK_THREADS + tid;
        const int j = idx >> 7;
        const int k = idx & 127;
        wt_lds[(k << 7) | (j ^ ((2 * k) & 62))] = W[idx];
    }
    __syncthreads();

    const int lane = tid & 63;
    const int wave = __builtin_amdgcn_readfirstlane(tid >> 6);
    const int gw = blockIdx.x * WAVES_PER_BLOCK + wave;  // wave-uniform

    const float2* emb2 = (const float2*)emb;
    const float2* b2   = (const float2*)bias;
    float2* out2       = (float2*)out;

    const int r0 = gw;                // row a
    const int r1 = gw + TOTAL_WAVES;  // row b

    // ---- gather-sum phase (both rows) ----
    float2 acc0, acc1;
#pragma unroll
    for (int rr = 0; rr < 2; ++rr) {
        const int r = (rr == 0) ? r0 : r1;
        const int hl = __builtin_amdgcn_readfirstlane(hist_len[r]);
        float2 a = make_float2(0.0f, 0.0f);
        if (hl == 0) {
            a = emb2[(size_t)entities[r] * 64 + lane];
        } else {
            const int* hrow = history + r * L_SZ;
            int l = 0;
            for (; l + 4 <= hl; l += 4) {  // MLP = 4 gathers in flight
                const int i0 = hrow[l + 0];
                const int i1 = hrow[l + 1];
                const int i2 = hrow[l + 2];
                const int i3 = hrow[l + 3];
                float2 v0 = emb2[(size_t)i0 * 64 + lane];
                float2 v1 = emb2[(size_t)i1 * 64 + lane];
                float2 v2 = emb2[(size_t)i2 * 64 + lane];
                float2 v3 = emb2[(size_t)i3 * 64 + lane];
                a.x += (v0.x + v1.x) + (v2.x + v3.x);
                a.y += (v0.y + v1.y) + (v2.y + v3.y);
            }
            for (; l < hl; ++l) {
                float2 v = emb2[(size_t)hrow[l] * 64 + lane];
                a.x += v.x;
                a.y += v.y;
            }
        }
        if (rr == 0) acc0 = a; else acc1 = a;
    }

    // ---- matmul phase: out[r][j] = b[j] + sum_k s[k]*WT[k][j] ----
    // lane owns j0=2*lane, j0+1; WT line shared across both rows (halves LDS traffic).
    float2 oa = b2[lane];
    float2 ob = oa;
    const int j0 = lane << 1;
#pragma unroll 4
    for (int k2 = 0; k2 < 64; ++k2) {
        const int ke = 2 * k2;      // even k
        const int ko = 2 * k2 + 1;  // odd k
        const float sa0 = __uint_as_float(
            __builtin_amdgcn_readlane(__float_as_uint(acc0.x), k2));
        const float sa1 = __uint_as_float(
            __builtin_amdgcn_readlane(__float_as_uint(acc0.y), k2));
        const float sb0 = __uint_as_float(
            __builtin_amdgcn_readlane(__float_as_uint(acc1.x), k2));
        const float sb1 = __uint_as_float(
            __builtin_amdgcn_readlane(__float_as_uint(acc1.y), k2));
        const float2 w0 =
            *(const float2*)&wt_lds[(ke << 7) | (j0 ^ ((2 * ke) & 62))];
        const float2 w1 =
            *(const float2*)&wt_lds[(ko << 7) | (j0 ^ ((2 * ko) & 62))];
        oa.x = fmaf(sa0, w0.x, oa.x);
        oa.y = fmaf(sa0, w0.y, oa.y);
        oa.x = fmaf(sa1, w1.x, oa.x);
        oa.y = fmaf(sa1, w1.y, oa.y);
        ob.x = fmaf(sb0, w0.x, ob.x);
        ob.y = fmaf(sb0, w0.y, ob.y);
        ob.x = fmaf(sb1, w1.x, ob.x);
        ob.y = fmaf(sb1, w1.y, ob.y);
    }
    out2[(size_t)r0 * 64 + lane] = oa;
    out2[(size_t)r1 * 64 + lane] = ob;
}

extern "C" void kernel_launch(void* const* d_in, const int* in_sizes, int n_in,
                              void* d_out, int out_size, void* d_ws,
                              size_t ws_size, hipStream_t stream) {
    const int* entities = (const int*)d_in[0];
    const int* history  = (const int*)d_in[1];
    const int* hist_len = (const int*)d_in[2];
    const float* emb    = (const float*)d_in[3];
    const float* W      = (const float*)d_in[4];
    const float* bias   = (const float*)d_in[5];

    fused_event_emb_kernel<<<GRID_BLOCKS, BLOCK_THREADS, 0, stream>>>(
        entities, history, hist_len, emb, W, bias, (float*)d_out);
}